// Round 18
// baseline (221.898 us; speedup 1.0000x reference)
//
#include <hip/hip_runtime.h>
#include <hip/hip_bf16.h>

#define DEVI __device__ __forceinline__

typedef float f32x4 __attribute__((ext_vector_type(4)));
typedef short s16x8 __attribute__((ext_vector_type(8)));

constexpr int T_ = 64;    // window
constexpr int F_ = 16;    // features
constexpr int H_ = 128;   // hidden
constexpr int NSEQ_ = 1024;
constexpr int NB_ = 2;    // sequences per block (MFMA N cols 2..15 = dups)
constexpr int NBLK_ = NSEQ_ / NB_;  // 512 blocks -> 2 resident blocks per CU
// NOTE: __launch_bounds__ stays (512,2) -- round 13 showed (512,4) causes a
// 64-reg spill catastrophe. At VGPR=96 / LDS 52KB the HARDWARE fits 2 blocks
// per CU; independent blocks slip past each other's barriers (latency hiding).

DEVI float sigmoidf_(float x) { return 1.0f / (1.0f + __expf(-x)); }
DEVI float tanhf_(float x) {
    float a = fabsf(x);
    float e = __expf(-2.0f * a);
    return copysignf((1.0f - e) / (1.0f + e), x);
}
DEVI ushort f2h(float f) {              // fp32 -> fp16 bits
    _Float16 h = (_Float16)f;
    ushort b; __builtin_memcpy(&b, &h, 2); return b;
}
DEVI float h2f(ushort b) {
    _Float16 h; __builtin_memcpy(&h, &b, 2); return (float)h;
}

#define MFMA16(A,B,C) __builtin_amdgcn_mfma_f32_16x16x32_f16((A),(B),(C),0,0,0)

// In-loop barrier: order LDS ops only (lgkmcnt); rep global stores float
// across steps and are drained by the epilogue's full __syncthreads().
#define BAR_LDS() asm volatile("s_waitcnt lgkmcnt(0)\n\ts_barrier" ::: "memory")

// LDS pool, phase-aliased (52768 B; 2 blocks/CU -> 105 KB < 160 KB):
//  recurrence: xh ushort[2][1032] @0 (4128B)  [x fp16, 2 real seqs]
//              hA @8320 (5376B), hB @13696 (5376B)   [h fp16 ping-pong]
//  epilogue (recurrence regions dead):
//              w1h ushort[128][140] @0 (35840B)
//              a2s  float[16][128]  @35840
//              logitb float[16][64] @44032
//              alph   float[16][64] @48128
//              wab    float[132]    @52224
constexpr int XSTR = 1032;
constexpr int HSTR = 168;   // f16 per h row (336 B)
constexpr int OFF_HA  = 8320, OFF_HB = 13696;
constexpr int OFF_A2S = 35840, OFF_LOG = 44032, OFF_ALPH = 48128, OFF_WAB = 52224;
constexpr int POOL_BYTES = 52768;

__global__ __launch_bounds__(512, 2)
void alphastock_main(const float* __restrict__ x,
                     const float* __restrict__ W_ih, const float* __restrict__ W_hh,
                     const float* __restrict__ b_ih, const float* __restrict__ b_hh,
                     const float* __restrict__ w1, const float* __restrict__ b1,
                     const float* __restrict__ w2, const float* __restrict__ b2,
                     const float* __restrict__ wa, const float* __restrict__ ba,
                     const float* __restrict__ wq, const float* __restrict__ bq,
                     const float* __restrict__ wk, const float* __restrict__ bk,
                     const float* __restrict__ wvm, const float* __restrict__ bv,
                     ushort* __restrict__ rep,   // [1024][64][128] fp16 ws
                     float* __restrict__ qout, float* __restrict__ kout,
                     float* __restrict__ vout)
{
    __shared__ alignas(16) char pool_[POOL_BYTES];
    ushort* xh    = (ushort*)pool_;
    ushort* hA    = (ushort*)(pool_ + OFF_HA);
    ushort* hB    = (ushort*)(pool_ + OFF_HB);
    ushort* w1h   = (ushort*)pool_;                    // epilogue alias
    float*  a2s   = (float*)(pool_ + OFF_A2S);
    float*  logitb= (float*)(pool_ + OFF_LOG);
    float*  alph  = (float*)(pool_ + OFF_ALPH);
    float*  wab   = (float*)(pool_ + OFF_WAB);

    const int tid  = threadIdx.x;
    const int wv   = tid >> 6;        // wave 0..7
    const int lane = tid & 63;
    const int lN   = lane & 15;       // frag col (seq dup) / A-row-in-tile
    const int lK   = lane >> 4;       // k-group 0..3
    const int nb   = blockIdx.x * NB_;

    // ---- prologue: zero BOTH h buffers; stage x (2 seqs) -> LDS fp16 ----
    for (int i = tid; i < 10752 / 4; i += 512)
        ((unsigned*)(pool_ + OFF_HA))[i] = 0;          // hA + hB (contiguous)
    for (int idx = tid; idx < NB_ * T_ * F_; idx += 512) {   // 2048
        int s = idx >> 10, rem = idx & 1023;                 // rem = t*16+f
        xh[s * XSTR + rem] = f2h(x[(size_t)(nb + s) * 1024 + rem]);
    }

    // ---- A-frags Whh fp16, ROW-PERMUTED so no gather is needed ----
    // Tile row lN of tile mt holds gate (lN&3) of cell c = 16wv+4mt+(lN>>2):
    // orig row = 128*(lN&3) + c. acc[mt][r] = gate r of cell 16wv+4mt+lK,
    // seq col (lN&3) (seqs >=2 are dups of seq&1).
    s16x8 wf[4][4];
    #pragma unroll
    for (int mt = 0; mt < 4; ++mt) {
        const int ra = 128 * (lN & 3) + 16 * wv + 4 * mt + (lN >> 2);
        #pragma unroll
        for (int ks = 0; ks < 4; ++ks) {
            const float4* p = (const float4*)(W_hh + (size_t)ra * 128 + ks * 32 + lK * 8);
            float4 v0 = p[0], v1 = p[1];
            float w[8] = {v0.x,v0.y,v0.z,v0.w, v1.x,v1.y,v1.z,v1.w};
            #pragma unroll
            for (int i = 0; i < 8; ++i) wf[mt][ks][i] = (short)f2h(w[i]);
        }
    }
    // Wih fp16 frags (same row permutation): K=16 padded to 32; lK>=2 zero.
    s16x8 wif[4];
    #pragma unroll
    for (int mt = 0; mt < 4; ++mt) {
        const int ra = 128 * (lN & 3) + 16 * wv + 4 * mt + (lN >> 2);
        const float4* p = (const float4*)(W_ih + (size_t)ra * 16 + (lK & 1) * 8);
        float4 v0 = p[0], v1 = p[1];
        float w[8] = {v0.x,v0.y,v0.z,v0.w, v1.x,v1.y,v1.z,v1.w};
        #pragma unroll
        for (int i = 0; i < 8; ++i)
            wif[mt][i] = (short)((lK < 2) ? f2h(w[i]) : 0);
    }
    // bias for acc[mt][r] = gate r of cell 16wv+4mt+lK
    f32x4 bias4[4];
    #pragma unroll
    for (int mt = 0; mt < 4; ++mt)
        #pragma unroll
        for (int r = 0; r < 4; ++r) {
            int rr = 128 * r + 16 * wv + 4 * mt + lK;
            bias4[mt][r] = b_ih[rr] + b_hh[rr];
        }
    __syncthreads();

    // ---- recurrent loop: NO gather. Lane owns cell j* = 16wv+4(lN>>2)+lK,
    // seq col lN&3 (real seq = (lN&3)&1); gates = acc[lN>>2][0..3] by select.
    const int hoffR = (lN & 3) * HSTR;      // B-frag h read (dup rows valid)
    const ushort* xrow = xh + (lN & 1) * XSTR + (lK & 1) * 8;
    const int  mtSel  = lN >> 2;
    const bool selLo  = (mtSel < 2);
    const bool selOdd = (mtSel & 1);
    const bool sel3   = (mtSel == 3);
    const int slocR = lN & 3;               // 0..3; real seqs 0..1
    const int hwoff = slocR * HSTR + 16 * wv + 4 * (lN >> 2) + lK;
    ushort* repL = rep + ((size_t)(nb + (slocR & 1)) * T_) * H_
                       + 16 * wv + 4 * (lN >> 2) + lK;
    const f32x4 zc = {0.f, 0.f, 0.f, 0.f};
    float cst = 0.f;
    #pragma unroll 1
    for (int tb = 0; tb < 16; ++tb) {
        s16x8 bx0 = *(const s16x8*)(xrow + (4 * tb + 0) * 16);
        s16x8 bx1 = *(const s16x8*)(xrow + (4 * tb + 1) * 16);
        s16x8 bx2 = *(const s16x8*)(xrow + (4 * tb + 2) * 16);
        s16x8 bx3 = *(const s16x8*)(xrow + (4 * tb + 3) * 16);
        #pragma unroll
        for (int u = 0; u < 4; ++u) {
            const int t = 4 * tb + u;
            s16x8 bx = (u == 0) ? bx0 : (u == 1) ? bx1 : (u == 2) ? bx2 : bx3;

            const ushort* hh = (u & 1) ? hB : hA;     // compile-time select
            s16x8 bh0 = *(const s16x8*)(hh + hoffR + 0 * 32 + lK * 8);
            s16x8 bh1 = *(const s16x8*)(hh + hoffR + 1 * 32 + lK * 8);
            s16x8 bh2 = *(const s16x8*)(hh + hoffR + 2 * 32 + lK * 8);
            s16x8 bh3 = *(const s16x8*)(hh + hoffR + 3 * 32 + lK * 8);

            // two parallel chains per tile: (wif->ks0->ks1) || (ks2->ks3)
            f32x4 a0 = MFMA16(wif[0], bx, bias4[0]);
            f32x4 a1 = MFMA16(wif[1], bx, bias4[1]);
            f32x4 a2 = MFMA16(wif[2], bx, bias4[2]);
            f32x4 a3 = MFMA16(wif[3], bx, bias4[3]);
            a0 = MFMA16(wf[0][0], bh0, a0); a1 = MFMA16(wf[1][0], bh0, a1);
            a2 = MFMA16(wf[2][0], bh0, a2); a3 = MFMA16(wf[3][0], bh0, a3);
            a0 = MFMA16(wf[0][1], bh1, a0); a1 = MFMA16(wf[1][1], bh1, a1);
            a2 = MFMA16(wf[2][1], bh1, a2); a3 = MFMA16(wf[3][1], bh1, a3);
            f32x4 d0 = MFMA16(wf[0][2], bh2, zc);
            f32x4 d1 = MFMA16(wf[1][2], bh2, zc);
            f32x4 d2 = MFMA16(wf[2][2], bh2, zc);
            f32x4 d3 = MFMA16(wf[3][2], bh2, zc);
            d0 = MFMA16(wf[0][3], bh3, d0); d1 = MFMA16(wf[1][3], bh3, d1);
            d2 = MFMA16(wf[2][3], bh3, d2); d3 = MFMA16(wf[3][3], bh3, d3);

            // 4-way register select by mtSel (3 cndmask per gate), fp32
            float g0s, g1s, g2s, g3s;
            {
                float p0 = a0[0] + d0[0], p1 = a1[0] + d1[0];
                float p2 = a2[0] + d2[0], p3 = a3[0] + d3[0];
                g0s = selLo ? (selOdd ? p1 : p0) : (sel3 ? p3 : p2);
                p0 = a0[1] + d0[1]; p1 = a1[1] + d1[1];
                p2 = a2[1] + d2[1]; p3 = a3[1] + d3[1];
                g1s = selLo ? (selOdd ? p1 : p0) : (sel3 ? p3 : p2);
                p0 = a0[2] + d0[2]; p1 = a1[2] + d1[2];
                p2 = a2[2] + d2[2]; p3 = a3[2] + d3[2];
                g2s = selLo ? (selOdd ? p1 : p0) : (sel3 ? p3 : p2);
                p0 = a0[3] + d0[3]; p1 = a1[3] + d1[3];
                p2 = a2[3] + d2[3]; p3 = a3[3] + d3[3];
                g3s = selLo ? (selOdd ? p1 : p0) : (sel3 ? p3 : p2);
            }

            // ONE cell update per lane (fp32 preacts)
            float ii = sigmoidf_(g0s);
            float ff = sigmoidf_(g1s);
            float gt = tanhf_(g2s);
            float oo = sigmoidf_(g3s);
            float c  = ff * cst + ii * gt;
            cst = c;
            ushort hb = f2h(oo * tanhf_(c));

            ushort* hw = (u & 1) ? hA : hB;           // write the OTHER buffer
            hw[hwoff] = hb;                           // 2B LDS write
            if (slocR < NB_)
                repL[(size_t)t * H_] = hb;            // real seqs only
            BAR_LDS();                                // LDS-only barrier
        }
    }

    // ================= epilogue (2 seqs in this block) =================
    // E0: stage w1 (fp16, stride 140) + wa/ba  (recurrence LDS dead)
    for (int idx = tid; idx < 128 * 128; idx += 512) {
        int o = idx >> 7, k = idx & 127;
        w1h[o * 140 + k] = f2h(w1[idx]);
    }
    if (tid < 128) wab[tid] = wa[tid];
    if (tid == 128) wab[128] = ba[0];
    __syncthreads();   // FULL barrier: drains vmcnt(0) -> rep stores visible

    // E1: a2[s][o] = h63 @ w2^T + b1 + b2  (wave 0; A rows dup of row&1)
    if (wv == 0) {
        s16x8 ar[4];
        #pragma unroll
        for (int ks = 0; ks < 4; ++ks)
            ar[ks] = *(const s16x8*)(rep + ((size_t)(nb + (lN & 1)) * T_ + 63) * H_ + ks * 32 + lK * 8);
        #pragma unroll
        for (int nt = 0; nt < 8; ++nt) {
            f32x4 acc = {0.f,0.f,0.f,0.f};
            const int o = 16 * nt + lN;
            #pragma unroll
            for (int ks = 0; ks < 4; ++ks) {
                const float4* p = (const float4*)(w2 + (size_t)o * 128 + ks * 32 + lK * 8);
                float4 v0 = p[0], v1 = p[1];
                s16x8 bb;
                bb[0]=(short)f2h(v0.x); bb[1]=(short)f2h(v0.y); bb[2]=(short)f2h(v0.z); bb[3]=(short)f2h(v0.w);
                bb[4]=(short)f2h(v1.x); bb[5]=(short)f2h(v1.y); bb[6]=(short)f2h(v1.z); bb[7]=(short)f2h(v1.w);
                acc = MFMA16(ar[ks], bb, acc);
            }
            float bb12 = b1[o] + b2[o];
            #pragma unroll
            for (int r = 0; r < 4; ++r)
                a2s[(4 * lK + r) * 128 + o] = acc[r] + bb12;   // row s: seq s&1
        }
    }
    __syncthreads();

    // E2: logits[t] = sum_o wa[o]*tanh((rep @ w1^T)[t][o] + a2[o])
    // 4 waves per seq: seq = wv>>2 (0..1), mt = wv&3
    {
        const int seq = wv >> 2;
        const int mt  = wv & 3;
        s16x8 ar[4];
        #pragma unroll
        for (int ks = 0; ks < 4; ++ks)
            ar[ks] = *(const s16x8*)(rep + ((size_t)(nb + seq) * T_ + 16 * mt + lN) * H_ + ks * 32 + lK * 8);
        float part[4] = {0.f,0.f,0.f,0.f};
        #pragma unroll
        for (int nt = 0; nt < 8; ++nt) {
            f32x4 acc = {0.f,0.f,0.f,0.f};
            #pragma unroll
            for (int ks = 0; ks < 4; ++ks)
                acc = MFMA16(ar[ks],
                             *(const s16x8*)(w1h + (lN + 16 * nt) * 140 + ks * 32 + lK * 8),
                             acc);
            const int o = lN + 16 * nt;
            const float wao = wab[o];
            const float a2o = a2s[seq * 128 + o];
            #pragma unroll
            for (int r = 0; r < 4; ++r)
                part[r] += wao * tanhf_(acc[r] + a2o);
        }
        #pragma unroll
        for (int r = 0; r < 4; ++r) {
            part[r] += __shfl_xor(part[r], 1);
            part[r] += __shfl_xor(part[r], 2);
            part[r] += __shfl_xor(part[r], 4);
            part[r] += __shfl_xor(part[r], 8);
        }
        if (lN == 0) {
            float4 st; st.x = part[0]; st.y = part[1]; st.z = part[2]; st.w = part[3];
            *(float4*)(logitb + seq * 64 + 16 * mt + 4 * lK) = st;  // t = 16mt+4lK+r
        }
    }
    __syncthreads();

    // E3: softmax over 64 logits, seq = wv (waves 0..1)
    if (wv < NB_) {
        const int seq = wv;
        float vl = logitb[seq * 64 + lane] + wab[128];
        float m = vl;
        #pragma unroll
        for (int off = 1; off < 64; off <<= 1) m = fmaxf(m, __shfl_xor(m, off));
        float e = __expf(vl - m);
        float ss = e;
        #pragma unroll
        for (int off = 1; off < 64; off <<= 1) ss += __shfl_xor(ss, off);
        alph[seq * 64 + lane] = e / ss;
    }
    __syncthreads();

    // E4: stock_rep[s][h] = sum_t alpha * rep  (fp32, into a2s alias)
    {
        const int s = (tid >> 7) & (NB_ - 1);      // dup for upper half
        const int o = tid & 127;
        float acc = 0.f;
        const ushort* rp = rep + (size_t)(nb + s) * T_ * H_ + o;
        #pragma unroll 8
        for (int t = 0; t < T_; ++t)
            acc += alph[s * 64 + t] * h2f(rp[(size_t)t * H_]);
        __syncthreads();                           // a2s readers (E2) done
        if (tid < NB_ * 128)
            a2s[s * 128 + o] = acc;
    }
    __syncthreads();

    // E5: q,k,v = sr @ W^T + b  (fp32 VALU; one seq per thread-group)
    {
        const float* sr = a2s;
        const int o = tid & 127, sg = tid >> 7;    // sg 0..3, real 0..1
        if (sg < NB_) {
            float aq = 0.f, ak = 0.f, av = 0.f;
            for (int k = 0; k < 128; k += 4) {
                float4 q4 = *(const float4*)(wq  + (size_t)o * 128 + k);
                float4 k4 = *(const float4*)(wk  + (size_t)o * 128 + k);
                float4 v4 = *(const float4*)(wvm + (size_t)o * 128 + k);
                float4 s4 = *(const float4*)(sr + sg * 128 + k);
                aq += q4.x*s4.x + q4.y*s4.y + q4.z*s4.z + q4.w*s4.w;
                ak += k4.x*s4.x + k4.y*s4.y + k4.z*s4.z + k4.w*s4.w;
                av += v4.x*s4.x + v4.y*s4.y + v4.z*s4.z + v4.w*s4.w;
            }
            qout[(size_t)(nb + sg) * H_ + o] = aq + bq[o];
            kout[(size_t)(nb + sg) * H_ + o] = ak + bk[o];
            vout[(size_t)(nb + sg) * H_ + o] = av + bv[o];
        }
    }
}

// Cross-asset attention: one block per (b, m) query row, 256 threads. fp32 out.
__global__ __launch_bounds__(256, 4)
void caan(const float* __restrict__ qb, const float* __restrict__ kb,
          const float* __restrict__ vb, const float* __restrict__ ww,
          const float* __restrict__ bw, float* __restrict__ out)
{
    __shared__ alignas(16) float qs[H_];
    __shared__ alignas(16) float sc[512];
    __shared__ alignas(16) float red[8];
    __shared__ alignas(16) float pv[2][H_];

    const int n   = blockIdx.x;
    const int b   = n >> 9;
    const int tid = threadIdx.x;

    if (tid < H_) qs[tid] = qb[n * H_ + tid];
    __syncthreads();

    const float scale = 0.08838834764831845f;  // 1/sqrt(128)
    float s0raw = 0.f, s1raw = 0.f;
    #pragma unroll
    for (int r = 0; r < 2; ++r) {
        const int j = tid + r * 256;
        const float4* kp = (const float4*)(kb + (size_t)(b * 512 + j) * H_);
        const float4* qp = (const float4*)qs;
        float c0=0.f,c1=0.f,c2=0.f,c3=0.f;
        #pragma unroll
        for (int i = 0; i < 32; ++i) {
            float4 kv = kp[i], qv = qp[i];
            c0 += kv.x*qv.x; c1 += kv.y*qv.y; c2 += kv.z*qv.z; c3 += kv.w*qv.w;
        }
        float sres = ((c0 + c1) + (c2 + c3)) * scale;
        if (r == 0) s0raw = sres; else s1raw = sres;
    }

    float m = fmaxf(s0raw, s1raw);
    #pragma unroll
    for (int off = 1; off < 64; off <<= 1) m = fmaxf(m, __shfl_xor(m, off));
    if ((tid & 63) == 0) red[tid >> 6] = m;
    __syncthreads();
    m = fmaxf(fmaxf(red[0], red[1]), fmaxf(red[2], red[3]));
    float e0 = __expf(s0raw - m), e1 = __expf(s1raw - m);
    sc[tid] = e0; sc[tid + 256] = e1;
    float lsum = e0 + e1;
    #pragma unroll
    for (int off = 1; off < 64; off <<= 1) lsum += __shfl_xor(lsum, off);
    if ((tid & 63) == 0) red[4 + (tid >> 6)] = lsum;
    __syncthreads();
    const float inv = 1.0f / ((red[4] + red[5]) + (red[6] + red[7]));

    const int o  = tid & (H_ - 1);
    const int jh = tid >> 7;
    const float* vp = vb + (size_t)(b * 512 + jh * 256) * H_ + o;
    float a0=0.f,a1=0.f,a2=0.f,a3=0.f;
    for (int j = 0; j < 256; j += 4) {
        a0 += sc[jh*256 + j + 0] * vp[(size_t)(j + 0) * H_];
        a1 += sc[jh*256 + j + 1] * vp[(size_t)(j + 1) * H_];
        a2 += sc[jh*256 + j + 2] * vp[(size_t)(j + 2) * H_];
        a3 += sc[jh*256 + j + 3] * vp[(size_t)(j + 3) * H_];
    }
    pv[jh][o] = (a0 + a1) + (a2 + a3);
    __syncthreads();
    if (tid < H_) {
        float s = (pv[0][tid] + pv[1][tid]) * inv * ww[tid];
        s += __shfl_xor(s, 1);  s += __shfl_xor(s, 2);  s += __shfl_xor(s, 4);
        s += __shfl_xor(s, 8);  s += __shfl_xor(s, 16); s += __shfl_xor(s, 32);
        if ((tid & 63) == 0) red[tid >> 6] = s;
    }
    __syncthreads();
    if (tid == 0) out[n] = red[0] + red[1] + bw[0];
}

extern "C" void kernel_launch(void* const* d_in, const int* in_sizes, int n_in,
                              void* d_out, int out_size, void* d_ws, size_t ws_size,
                              hipStream_t stream)
{
    const float* x    = (const float*)d_in[0];
    const float* W_ih = (const float*)d_in[1];
    const float* W_hh = (const float*)d_in[2];
    const float* b_ih = (const float*)d_in[3];
    const float* b_hh = (const float*)d_in[4];
    const float* w1   = (const float*)d_in[5];
    const float* b1   = (const float*)d_in[6];
    const float* w2   = (const float*)d_in[7];
    const float* b2   = (const float*)d_in[8];
    const float* wa   = (const float*)d_in[9];
    const float* ba   = (const float*)d_in[10];
    const float* wq   = (const float*)d_in[11];
    const float* bq   = (const float*)d_in[12];
    const float* wk   = (const float*)d_in[13];
    const float* bk   = (const float*)d_in[14];
    const float* wv   = (const float*)d_in[15];
    const float* bv   = (const float*)d_in[16];
    const float* ww   = (const float*)d_in[17];
    const float* bw   = (const float*)d_in[18];

    float* ws   = (float*)d_ws;
    float* qbuf = ws;                              // 1024*128 f32
    float* kbuf = ws + (size_t)NSEQ_ * H_;
    float* vbuf = ws + (size_t)2 * NSEQ_ * H_;
    ushort* rep = (ushort*)(ws + (size_t)3 * NSEQ_ * H_);        // 16 MB fp16

    alphastock_main<<<NBLK_, 512, 0, stream>>>(x, W_ih, W_hh, b_ih, b_hh,
                                               w1, b1, w2, b2, wa, ba,
                                               wq, bq, wk, bk, wv, bv,
                                               rep, qbuf, kbuf, vbuf);
    caan<<<NSEQ_, 256, 0, stream>>>(qbuf, kbuf, vbuf, ww, bw, (float*)d_out);
}

// Round 19
// 126.943 us; speedup vs baseline: 1.7480x; 1.7480x over previous
//
#include <hip/hip_runtime.h>
#include <hip/hip_bf16.h>

#define DEVI __device__ __forceinline__

typedef float f32x4 __attribute__((ext_vector_type(4)));
typedef short s16x8 __attribute__((ext_vector_type(8)));

constexpr int T_ = 64;    // window
constexpr int F_ = 16;    // features
constexpr int H_ = 128;   // hidden
constexpr int NSEQ_ = 1024;
constexpr int NB_ = 4;    // sequences per block (MFMA N cols 4..15 = dups)
constexpr int NBLK_ = NSEQ_ / NB_;  // 256 blocks -> every CU gets one block
// NB=4 is work-optimal: per-block recurrence cost is FIXED (all 512 gate rows
// computed regardless of NB), so NB=2/512-blocks doubles device work (round 18
// regression: 127->192 us despite higher MfmaUtil).

DEVI float sigmoidf_(float x) { return 1.0f / (1.0f + __expf(-x)); }
DEVI float tanhf_(float x) {
    float a = fabsf(x);
    float e = __expf(-2.0f * a);
    return copysignf((1.0f - e) / (1.0f + e), x);
}
DEVI ushort f2h(float f) {              // fp32 -> fp16 bits
    _Float16 h = (_Float16)f;
    ushort b; __builtin_memcpy(&b, &h, 2); return b;
}
DEVI float h2f(ushort b) {
    _Float16 h; __builtin_memcpy(&h, &b, 2); return (float)h;
}

#define MFMA16(A,B,C) __builtin_amdgcn_mfma_f32_16x16x32_f16((A),(B),(C),0,0,0)

// In-loop barrier: order LDS ops only (lgkmcnt); rep global stores float
// across steps and are drained by the epilogue's full __syncthreads().
#define BAR_LDS() asm volatile("s_waitcnt lgkmcnt(0)\n\ts_barrier" ::: "memory")

// LDS pool, phase-aliased (52768 B):
//  recurrence: xh ushort[4][1032] @0 (8256B)  [x fp16, 4 real seqs]
//              hA @8320 (5376B), hB @13696 (5376B)   [h fp16 ping-pong]
//  epilogue (recurrence regions dead):
//              w1h ushort[128][140] @0 (35840B)
//              a2s  float[16][128]  @35840
//              logitb float[16][64] @44032
//              alph   float[16][64] @48128
//              wab    float[132]    @52224
constexpr int XSTR = 1032;
constexpr int HSTR = 168;   // f16 per h row (336 B)
constexpr int OFF_HA  = 8320, OFF_HB = 13696;
constexpr int OFF_A2S = 35840, OFF_LOG = 44032, OFF_ALPH = 48128, OFF_WAB = 52224;
constexpr int POOL_BYTES = 52768;

__global__ __launch_bounds__(512, 2)
void alphastock_main(const float* __restrict__ x,
                     const float* __restrict__ W_ih, const float* __restrict__ W_hh,
                     const float* __restrict__ b_ih, const float* __restrict__ b_hh,
                     const float* __restrict__ w1, const float* __restrict__ b1,
                     const float* __restrict__ w2, const float* __restrict__ b2,
                     const float* __restrict__ wa, const float* __restrict__ ba,
                     const float* __restrict__ wq, const float* __restrict__ bq,
                     const float* __restrict__ wk, const float* __restrict__ bk,
                     const float* __restrict__ wvm, const float* __restrict__ bv,
                     ushort* __restrict__ rep,   // [1024][64][128] fp16 ws
                     float* __restrict__ qout, float* __restrict__ kout,
                     float* __restrict__ vout)
{
    __shared__ alignas(16) char pool_[POOL_BYTES];
    ushort* xh    = (ushort*)pool_;
    ushort* hA    = (ushort*)(pool_ + OFF_HA);
    ushort* hB    = (ushort*)(pool_ + OFF_HB);
    ushort* w1h   = (ushort*)pool_;                    // epilogue alias
    float*  a2s   = (float*)(pool_ + OFF_A2S);
    float*  logitb= (float*)(pool_ + OFF_LOG);
    float*  alph  = (float*)(pool_ + OFF_ALPH);
    float*  wab   = (float*)(pool_ + OFF_WAB);

    const int tid  = threadIdx.x;
    const int wv   = tid >> 6;        // wave 0..7
    const int lane = tid & 63;
    const int lN   = lane & 15;       // frag col (seq dup-4) / A-row-in-tile
    const int lK   = lane >> 4;       // k-group 0..3
    const int nb   = blockIdx.x * NB_;

    // ---- prologue: zero BOTH h buffers; stage x (4 seqs) -> LDS fp16 ----
    for (int i = tid; i < 10752 / 4; i += 512)
        ((unsigned*)(pool_ + OFF_HA))[i] = 0;          // hA + hB (contiguous)
    for (int idx = tid; idx < NB_ * T_ * F_; idx += 512) {   // 4096
        int s = idx >> 10, rem = idx & 1023;                 // rem = t*16+f
        xh[s * XSTR + rem] = f2h(x[(size_t)(nb + s) * 1024 + rem]);
    }

    // ---- A-frags Whh fp16, ROW-PERMUTED so the gather disappears ----
    s16x8 wf[4][4];
    #pragma unroll
    for (int mt = 0; mt < 4; ++mt) {
        const int ra = 128 * (lN & 3) + 16 * wv + 4 * mt + (lN >> 2);
        #pragma unroll
        for (int ks = 0; ks < 4; ++ks) {
            const float4* p = (const float4*)(W_hh + (size_t)ra * 128 + ks * 32 + lK * 8);
            float4 v0 = p[0], v1 = p[1];
            float w[8] = {v0.x,v0.y,v0.z,v0.w, v1.x,v1.y,v1.z,v1.w};
            #pragma unroll
            for (int i = 0; i < 8; ++i) wf[mt][ks][i] = (short)f2h(w[i]);
        }
    }
    // Wih fp16 frags (same row permutation): K=16 padded to 32; lK>=2 zero.
    s16x8 wif[4];
    #pragma unroll
    for (int mt = 0; mt < 4; ++mt) {
        const int ra = 128 * (lN & 3) + 16 * wv + 4 * mt + (lN >> 2);
        const float4* p = (const float4*)(W_ih + (size_t)ra * 16 + (lK & 1) * 8);
        float4 v0 = p[0], v1 = p[1];
        float w[8] = {v0.x,v0.y,v0.z,v0.w, v1.x,v1.y,v1.z,v1.w};
        #pragma unroll
        for (int i = 0; i < 8; ++i)
            wif[mt][i] = (short)((lK < 2) ? f2h(w[i]) : 0);
    }
    // bias for acc[mt][r] = gate r of cell 16wv+4mt+lK
    f32x4 bias4[4];
    #pragma unroll
    for (int mt = 0; mt < 4; ++mt)
        #pragma unroll
        for (int r = 0; r < 4; ++r) {
            int rr = 128 * r + 16 * wv + 4 * mt + lK;
            bias4[mt][r] = b_ih[rr] + b_hh[rr];
        }
    __syncthreads();

    // ---- recurrent loop: NO gather. Lane owns cell j* = 16wv+4(lN>>2)+lK,
    // seq lN&3; gates come from acc[lN>>2][0..3] via 4-way register select.
    const int hoffR = (lN & 3) * HSTR;      // B-frag h read (real seq row)
    const ushort* xrow = xh + (lN & 3) * XSTR + (lK & 1) * 8;
    const int  mtSel  = lN >> 2;
    const bool selLo  = (mtSel < 2);
    const bool selOdd = (mtSel & 1);
    const bool sel3   = (mtSel == 3);
    const int hwoff = (lN & 3) * HSTR + 16 * wv + 4 * (lN >> 2) + lK;
    ushort* repL = rep + ((size_t)(nb + (lN & 3)) * T_) * H_
                       + 16 * wv + 4 * (lN >> 2) + lK;
    const f32x4 zc = {0.f, 0.f, 0.f, 0.f};
    float cst = 0.f;
    #pragma unroll 1
    for (int tb = 0; tb < 16; ++tb) {
        s16x8 bx0 = *(const s16x8*)(xrow + (4 * tb + 0) * 16);
        s16x8 bx1 = *(const s16x8*)(xrow + (4 * tb + 1) * 16);
        s16x8 bx2 = *(const s16x8*)(xrow + (4 * tb + 2) * 16);
        s16x8 bx3 = *(const s16x8*)(xrow + (4 * tb + 3) * 16);
        #pragma unroll
        for (int u = 0; u < 4; ++u) {
            const int t = 4 * tb + u;
            s16x8 bx = (u == 0) ? bx0 : (u == 1) ? bx1 : (u == 2) ? bx2 : bx3;

            const ushort* hh = (u & 1) ? hB : hA;     // compile-time select
            s16x8 bh0 = *(const s16x8*)(hh + hoffR + 0 * 32 + lK * 8);
            s16x8 bh1 = *(const s16x8*)(hh + hoffR + 1 * 32 + lK * 8);
            s16x8 bh2 = *(const s16x8*)(hh + hoffR + 2 * 32 + lK * 8);
            s16x8 bh3 = *(const s16x8*)(hh + hoffR + 3 * 32 + lK * 8);

            // two parallel chains per tile: (wif->ks0->ks1) || (ks2->ks3)
            f32x4 a0 = MFMA16(wif[0], bx, bias4[0]);
            f32x4 a1 = MFMA16(wif[1], bx, bias4[1]);
            f32x4 a2 = MFMA16(wif[2], bx, bias4[2]);
            f32x4 a3 = MFMA16(wif[3], bx, bias4[3]);
            a0 = MFMA16(wf[0][0], bh0, a0); a1 = MFMA16(wf[1][0], bh0, a1);
            a2 = MFMA16(wf[2][0], bh0, a2); a3 = MFMA16(wf[3][0], bh0, a3);
            a0 = MFMA16(wf[0][1], bh1, a0); a1 = MFMA16(wf[1][1], bh1, a1);
            a2 = MFMA16(wf[2][1], bh1, a2); a3 = MFMA16(wf[3][1], bh1, a3);
            f32x4 d0 = MFMA16(wf[0][2], bh2, zc);
            f32x4 d1 = MFMA16(wf[1][2], bh2, zc);
            f32x4 d2 = MFMA16(wf[2][2], bh2, zc);
            f32x4 d3 = MFMA16(wf[3][2], bh2, zc);
            d0 = MFMA16(wf[0][3], bh3, d0); d1 = MFMA16(wf[1][3], bh3, d1);
            d2 = MFMA16(wf[2][3], bh3, d2); d3 = MFMA16(wf[3][3], bh3, d3);

            // 4-way register select by mtSel (3 cndmask per gate), fp32
            float g0s, g1s, g2s, g3s;
            {
                float p0 = a0[0] + d0[0], p1 = a1[0] + d1[0];
                float p2 = a2[0] + d2[0], p3 = a3[0] + d3[0];
                g0s = selLo ? (selOdd ? p1 : p0) : (sel3 ? p3 : p2);
                p0 = a0[1] + d0[1]; p1 = a1[1] + d1[1];
                p2 = a2[1] + d2[1]; p3 = a3[1] + d3[1];
                g1s = selLo ? (selOdd ? p1 : p0) : (sel3 ? p3 : p2);
                p0 = a0[2] + d0[2]; p1 = a1[2] + d1[2];
                p2 = a2[2] + d2[2]; p3 = a3[2] + d3[2];
                g2s = selLo ? (selOdd ? p1 : p0) : (sel3 ? p3 : p2);
                p0 = a0[3] + d0[3]; p1 = a1[3] + d1[3];
                p2 = a2[3] + d2[3]; p3 = a3[3] + d3[3];
                g3s = selLo ? (selOdd ? p1 : p0) : (sel3 ? p3 : p2);
            }

            // ONE cell update per lane (fp32 preacts)
            float ii = sigmoidf_(g0s);
            float ff = sigmoidf_(g1s);
            float gt = tanhf_(g2s);
            float oo = sigmoidf_(g3s);
            float c  = ff * cst + ii * gt;
            cst = c;
            ushort hb = f2h(oo * tanhf_(c));

            ushort* hw = (u & 1) ? hA : hB;           // write the OTHER buffer
            hw[hwoff] = hb;                           // 2B LDS write
            repL[(size_t)t * H_] = hb;                // 2B global (floats to L2)
            BAR_LDS();                                // LDS-only barrier
        }
    }

    // ================= epilogue (4 seqs in this block) =================
    // E0: stage w1 (fp16, stride 140) + wa/ba  (recurrence LDS dead)
    for (int idx = tid; idx < 128 * 128; idx += 512) {
        int o = idx >> 7, k = idx & 127;
        w1h[o * 140 + k] = f2h(w1[idx]);
    }
    if (tid < 128) wab[tid] = wa[tid];
    if (tid == 128) wab[128] = ba[0];
    __syncthreads();   // FULL barrier: drains vmcnt(0) -> rep stores visible

    // E1: a2[s][o] = h63 @ w2^T + b1 + b2  (wave 0; A rows >=4 dup of row&3)
    if (wv == 0) {
        s16x8 ar[4];
        #pragma unroll
        for (int ks = 0; ks < 4; ++ks)
            ar[ks] = *(const s16x8*)(rep + ((size_t)(nb + (lN & 3)) * T_ + 63) * H_ + ks * 32 + lK * 8);
        #pragma unroll
        for (int nt = 0; nt < 8; ++nt) {
            f32x4 acc = {0.f,0.f,0.f,0.f};
            const int o = 16 * nt + lN;
            #pragma unroll
            for (int ks = 0; ks < 4; ++ks) {
                const float4* p = (const float4*)(w2 + (size_t)o * 128 + ks * 32 + lK * 8);
                float4 v0 = p[0], v1 = p[1];
                s16x8 bb;
                bb[0]=(short)f2h(v0.x); bb[1]=(short)f2h(v0.y); bb[2]=(short)f2h(v0.z); bb[3]=(short)f2h(v0.w);
                bb[4]=(short)f2h(v1.x); bb[5]=(short)f2h(v1.y); bb[6]=(short)f2h(v1.z); bb[7]=(short)f2h(v1.w);
                acc = MFMA16(ar[ks], bb, acc);
            }
            float bb12 = b1[o] + b2[o];
            #pragma unroll
            for (int r = 0; r < 4; ++r)
                a2s[(4 * lK + r) * 128 + o] = acc[r] + bb12;   // seq = 4lK+r
        }
    }
    __syncthreads();

    // E2: logits[t] = sum_o wa[o]*tanh((rep @ w1^T)[t][o] + a2[o])
    // 2 waves per seq: seq = wv>>1, mt = (wv&1)*2 + mtl
    {
        const int seq = wv >> 1;
        #pragma unroll 1
        for (int mtl = 0; mtl < 2; ++mtl) {
            const int mt = (wv & 1) * 2 + mtl;
            s16x8 ar[4];
            #pragma unroll
            for (int ks = 0; ks < 4; ++ks)
                ar[ks] = *(const s16x8*)(rep + ((size_t)(nb + seq) * T_ + 16 * mt + lN) * H_ + ks * 32 + lK * 8);
            float part[4] = {0.f,0.f,0.f,0.f};
            #pragma unroll
            for (int nt = 0; nt < 8; ++nt) {
                f32x4 acc = {0.f,0.f,0.f,0.f};
                #pragma unroll
                for (int ks = 0; ks < 4; ++ks)
                    acc = MFMA16(ar[ks],
                                 *(const s16x8*)(w1h + (lN + 16 * nt) * 140 + ks * 32 + lK * 8),
                                 acc);
                const int o = lN + 16 * nt;
                const float wao = wab[o];
                const float a2o = a2s[seq * 128 + o];
                #pragma unroll
                for (int r = 0; r < 4; ++r)
                    part[r] += wao * tanhf_(acc[r] + a2o);
            }
            #pragma unroll
            for (int r = 0; r < 4; ++r) {
                part[r] += __shfl_xor(part[r], 1);
                part[r] += __shfl_xor(part[r], 2);
                part[r] += __shfl_xor(part[r], 4);
                part[r] += __shfl_xor(part[r], 8);
            }
            if (lN == 0) {
                float4 st; st.x = part[0]; st.y = part[1]; st.z = part[2]; st.w = part[3];
                *(float4*)(logitb + seq * 64 + 16 * mt + 4 * lK) = st;  // t = 16mt+4lK+r
            }
        }
    }
    __syncthreads();

    // E3: softmax over 64 logits, seq = wv (waves 0..3)
    if (wv < NB_) {
        const int seq = wv;
        float vl = logitb[seq * 64 + lane] + wab[128];
        float m = vl;
        #pragma unroll
        for (int off = 1; off < 64; off <<= 1) m = fmaxf(m, __shfl_xor(m, off));
        float e = __expf(vl - m);
        float ss = e;
        #pragma unroll
        for (int off = 1; off < 64; off <<= 1) ss += __shfl_xor(ss, off);
        alph[seq * 64 + lane] = e / ss;
    }
    __syncthreads();

    // E4: stock_rep[s][h] = sum_t alpha * rep  (fp32, into a2s alias)
    {
        const int s = tid >> 7, o = tid & 127;     // 1 element per thread
        float acc = 0.f;
        const ushort* rp = rep + (size_t)(nb + s) * T_ * H_ + o;
        #pragma unroll 8
        for (int t = 0; t < T_; ++t)
            acc += alph[s * 64 + t] * h2f(rp[(size_t)t * H_]);
        __syncthreads();                           // a2s readers (E2) done
        a2s[s * 128 + o] = acc;
    }
    __syncthreads();

    // E5: q,k,v = sr @ W^T + b  (fp32 VALU; one seq per thread-group)
    {
        const float* sr = a2s;
        const int o = tid & 127, sg = tid >> 7;    // sg = seq 0..3
        float aq = 0.f, ak = 0.f, av = 0.f;
        for (int k = 0; k < 128; k += 4) {
            float4 q4 = *(const float4*)(wq  + (size_t)o * 128 + k);
            float4 k4 = *(const float4*)(wk  + (size_t)o * 128 + k);
            float4 v4 = *(const float4*)(wvm + (size_t)o * 128 + k);
            float4 s4 = *(const float4*)(sr + sg * 128 + k);
            aq += q4.x*s4.x + q4.y*s4.y + q4.z*s4.z + q4.w*s4.w;
            ak += k4.x*s4.x + k4.y*s4.y + k4.z*s4.z + k4.w*s4.w;
            av += v4.x*s4.x + v4.y*s4.y + v4.z*s4.z + v4.w*s4.w;
        }
        qout[(size_t)(nb + sg) * H_ + o] = aq + bq[o];
        kout[(size_t)(nb + sg) * H_ + o] = ak + bk[o];
        vout[(size_t)(nb + sg) * H_ + o] = av + bv[o];
    }
}

// Cross-asset attention, 4 QUERIES PER BLOCK (K/V traffic amortized 4x).
// 256 blocks x 512 threads. fp32 throughout.
__global__ __launch_bounds__(512, 2)
void caan4(const float* __restrict__ qb, const float* __restrict__ kb,
           const float* __restrict__ vb, const float* __restrict__ ww,
           const float* __restrict__ bw, float* __restrict__ out)
{
    __shared__ alignas(16) float qs[4][H_];       // 2 KB
    __shared__ alignas(16) float sc[4][512];      // 8 KB (scores -> betas)
    __shared__ alignas(16) float pv[4][4][H_];    // 8 KB (quarter partials)

    const int nb  = blockIdx.x * 4;               // queries nb..nb+3
    const int b   = nb >> 9;                      // batch (groups don't straddle)
    const int tid = threadIdx.x;

    for (int i = tid; i < 4 * H_; i += 512) {
        int q = i >> 7, o = i & 127;
        qs[q][o] = qb[(size_t)(nb + q) * H_ + o];
    }
    __syncthreads();

    const float scale = 0.08838834764831845f;     // 1/sqrt(128)
    // scores: thread tid owns k-row tid; k element loaded once, 4 FMAs
    {
        const float4* kp = (const float4*)(kb + (size_t)(b * 512 + tid) * H_);
        float acc0 = 0.f, acc1 = 0.f, acc2 = 0.f, acc3 = 0.f;
        #pragma unroll 8
        for (int i = 0; i < 32; ++i) {
            float4 kv = kp[i];
            const float4 q0 = *(const float4*)(&qs[0][i * 4]);
            const float4 q1 = *(const float4*)(&qs[1][i * 4]);
            const float4 q2 = *(const float4*)(&qs[2][i * 4]);
            const float4 q3 = *(const float4*)(&qs[3][i * 4]);
            acc0 += kv.x*q0.x + kv.y*q0.y + kv.z*q0.z + kv.w*q0.w;
            acc1 += kv.x*q1.x + kv.y*q1.y + kv.z*q1.z + kv.w*q1.w;
            acc2 += kv.x*q2.x + kv.y*q2.y + kv.z*q2.z + kv.w*q2.w;
            acc3 += kv.x*q3.x + kv.y*q3.y + kv.z*q3.z + kv.w*q3.w;
        }
        sc[0][tid] = acc0 * scale;
        sc[1][tid] = acc1 * scale;
        sc[2][tid] = acc2 * scale;
        sc[3][tid] = acc3 * scale;
    }
    __syncthreads();

    // softmax per query: wave w (0..3) handles query w; 8 values per lane
    if (tid < 256) {
        const int w = tid >> 6, lane = tid & 63;
        float v[8];
        float m = -INFINITY;
        #pragma unroll
        for (int i = 0; i < 8; ++i) { v[i] = sc[w][lane * 8 + i]; m = fmaxf(m, v[i]); }
        #pragma unroll
        for (int off = 1; off < 64; off <<= 1) m = fmaxf(m, __shfl_xor(m, off));
        float ss = 0.f;
        #pragma unroll
        for (int i = 0; i < 8; ++i) { v[i] = __expf(v[i] - m); ss += v[i]; }
        #pragma unroll
        for (int off = 1; off < 64; off <<= 1) ss += __shfl_xor(ss, off);
        float inv = 1.0f / ss;
        #pragma unroll
        for (int i = 0; i < 8; ++i) sc[w][lane * 8 + i] = v[i] * inv;
    }
    __syncthreads();

    // beta @ v: thread (o = tid&127, qt = tid>>7) covers 128 rows, 4 queries;
    // v element loaded once, 4 FMAs
    {
        const int o = tid & 127, qt = tid >> 7;
        const float* vp = vb + (size_t)(b * 512 + qt * 128) * H_ + o;
        float a0 = 0.f, a1 = 0.f, a2 = 0.f, a3 = 0.f;
        #pragma unroll 4
        for (int j = 0; j < 128; ++j) {
            float vv = vp[(size_t)j * H_];
            int row = qt * 128 + j;
            a0 += sc[0][row] * vv;
            a1 += sc[1][row] * vv;
            a2 += sc[2][row] * vv;
            a3 += sc[3][row] * vv;
        }
        pv[0][qt][o] = a0; pv[1][qt][o] = a1;
        pv[2][qt][o] = a2; pv[3][qt][o] = a3;
    }
    __syncthreads();

    // final: out[nb+w] = sum_o (sum_qt pv[w][qt][o]) * ww[o] + bw  (waves 0..3)
    if (tid < 256) {
        const int w = tid >> 6, lane = tid & 63;
        float sA = ((pv[w][0][lane] + pv[w][1][lane])
                  + (pv[w][2][lane] + pv[w][3][lane])) * ww[lane];
        float sB = ((pv[w][0][lane + 64] + pv[w][1][lane + 64])
                  + (pv[w][2][lane + 64] + pv[w][3][lane + 64])) * ww[lane + 64];
        float s = sA + sB;
        #pragma unroll
        for (int off = 1; off < 64; off <<= 1) s += __shfl_xor(s, off);
        if (lane == 0) out[nb + w] = s + bw[0];
    }
}

extern "C" void kernel_launch(void* const* d_in, const int* in_sizes, int n_in,
                              void* d_out, int out_size, void* d_ws, size_t ws_size,
                              hipStream_t stream)
{
    const float* x    = (const float*)d_in[0];
    const float* W_ih = (const float*)d_in[1];
    const float* W_hh = (const float*)d_in[2];
    const float* b_ih = (const float*)d_in[3];
    const float* b_hh = (const float*)d_in[4];
    const float* w1   = (const float*)d_in[5];
    const float* b1   = (const float*)d_in[6];
    const float* w2   = (const float*)d_in[7];
    const float* b2   = (const float*)d_in[8];
    const float* wa   = (const float*)d_in[9];
    const float* ba   = (const float*)d_in[10];
    const float* wq   = (const float*)d_in[11];
    const float* bq   = (const float*)d_in[12];
    const float* wk   = (const float*)d_in[13];
    const float* bk   = (const float*)d_in[14];
    const float* wv   = (const float*)d_in[15];
    const float* bv   = (const float*)d_in[16];
    const float* ww   = (const float*)d_in[17];
    const float* bw   = (const float*)d_in[18];

    float* ws   = (float*)d_ws;
    float* qbuf = ws;                              // 1024*128 f32
    float* kbuf = ws + (size_t)NSEQ_ * H_;
    float* vbuf = ws + (size_t)2 * NSEQ_ * H_;
    ushort* rep = (ushort*)(ws + (size_t)3 * NSEQ_ * H_);        // 16 MB fp16

    alphastock_main<<<NBLK_, 512, 0, stream>>>(x, W_ih, W_hh, b_ih, b_hh,
                                               w1, b1, w2, b2, wa, ba,
                                               wq, bq, wk, bk, wv, bv,
                                               rep, qbuf, kbuf, vbuf);
    caan4<<<NSEQ_ / 4, 512, 0, stream>>>(qbuf, kbuf, vbuf, ww, bw,
                                         (float*)d_out);
}